// Round 1
// baseline (2304.618 us; speedup 1.0000x reference)
//
#include <hip/hip_runtime.h>

#define NN   100000
#define NE   1600000
#define NRL  4
#define DIM  64
#define EPS  1e-10f

// workspace layout (bytes)
#define AGG_BYTES   102400000   // NN*NRL*DIM*4
#define DEG_BYTES   1600000     // NN*NRL*4
#define FEAT_BYTES  25600000    // NN*DIM*4

// ---------------------------------------------------------------------------
// Scatter: one wave per edge, lane = feature column.
// agg[(dst*4+rel)*64 + c] += x[src*64 + c] * ew ;  deg[dst*4+rel] += ew
// ---------------------------------------------------------------------------
__global__ __launch_bounds__(256) void k_scatter(
    const float* __restrict__ x, const float* __restrict__ ew,
    const int* __restrict__ src, const int* __restrict__ dst,
    const int* __restrict__ rel,
    float* __restrict__ agg, float* __restrict__ deg)
{
    const long long total  = (long long)NE * 64;
    const long long stride = (long long)gridDim.x * blockDim.x;
    for (long long gid = (long long)blockIdx.x * blockDim.x + threadIdx.x;
         gid < total; gid += stride) {
        int e = (int)(gid >> 6);
        int c = (int)(gid & 63);
        int b = dst[e] * NRL + rel[e];
        float w = ew[e];
        float m = x[(size_t)src[e] * DIM + c] * w;
        __hip_atomic_fetch_add(&agg[(size_t)b * DIM + c], m,
                               __ATOMIC_RELAXED, __HIP_MEMORY_SCOPE_AGENT);
        if (c == 0)
            __hip_atomic_fetch_add(&deg[b], w,
                                   __ATOMIC_RELAXED, __HIP_MEMORY_SCOPE_AGENT);
    }
}

// ---------------------------------------------------------------------------
// Conv: hidden = sigmoid(upd @ lin_w + lin_b + x @ self_w + self_b)
// upd[n, r*64+k] = agg[(n*4+r)*64+k] / (deg[n*4+r] + eps)
// lin_w (256x64) in LDS; self_w (64x64, 16KB) read from global (L1-resident).
// One wave per node; lane = output column.
// ---------------------------------------------------------------------------
__global__ __launch_bounds__(256, 2) void k_conv(
    const float* __restrict__ x,
    const float* __restrict__ agg, const float* __restrict__ deg,
    const float* __restrict__ lin_w, const float* __restrict__ lin_b,
    const float* __restrict__ self_w, const float* __restrict__ self_b,
    float* __restrict__ hid)
{
    __shared__ float s_w[256 * 64];   // 64 KB: lin_w
    __shared__ float s_b[64];
    __shared__ float s_in[4][320];    // per-wave: upd(256) + x(64)

    for (int i = threadIdx.x; i < 256 * 64; i += 256) s_w[i] = lin_w[i];
    if (threadIdx.x < 64)
        s_b[threadIdx.x] = lin_b[threadIdx.x] + self_b[threadIdx.x];
    __syncthreads();

    const int lane = threadIdx.x & 63;
    const int wid  = threadIdx.x >> 6;

    for (int n = blockIdx.x * 4 + wid; n < NN; n += gridDim.x * 4) {
        // stage upd + x for this node into the wave's LDS slot
        #pragma unroll
        for (int r = 0; r < 4; ++r) {
            float d = deg[n * 4 + r];
            s_in[wid][r * 64 + lane] =
                agg[((size_t)n * 4 + r) * 64 + lane] / (d + EPS);
        }
        s_in[wid][256 + lane] = x[(size_t)n * 64 + lane];

        float acc[4] = { s_b[lane], 0.f, 0.f, 0.f };

        // upd @ lin_w   (K = 256, LDS weights)
        #pragma unroll 8
        for (int k = 0; k < 256; k += 4) {
            float4 u = *(const float4*)&s_in[wid][k];
            acc[0] = fmaf(u.x, s_w[(k + 0) * 64 + lane], acc[0]);
            acc[1] = fmaf(u.y, s_w[(k + 1) * 64 + lane], acc[1]);
            acc[2] = fmaf(u.z, s_w[(k + 2) * 64 + lane], acc[2]);
            acc[3] = fmaf(u.w, s_w[(k + 3) * 64 + lane], acc[3]);
        }
        // x @ self_w    (K = 64, global weights, L1-resident 16KB)
        #pragma unroll 4
        for (int k = 0; k < 64; k += 4) {
            float4 u = *(const float4*)&s_in[wid][256 + k];
            acc[0] = fmaf(u.x, self_w[(k + 0) * 64 + lane], acc[0]);
            acc[1] = fmaf(u.y, self_w[(k + 1) * 64 + lane], acc[1]);
            acc[2] = fmaf(u.z, self_w[(k + 2) * 64 + lane], acc[2]);
            acc[3] = fmaf(u.w, self_w[(k + 3) * 64 + lane], acc[3]);
        }
        float o = (acc[0] + acc[1]) + (acc[2] + acc[3]);
        hid[(size_t)n * 64 + lane] = 1.0f / (1.0f + __expf(-o));
    }
}

// ---------------------------------------------------------------------------
// Highway: cat = [hid, prev];
// proj = relu(cat@pw + pb); gate = sigmoid(cat@tw + tb);
// out = gate*proj + (1-gate)*hid
// ---------------------------------------------------------------------------
__global__ __launch_bounds__(256, 2) void k_highway(
    const float* __restrict__ hid, const float* __restrict__ prev,
    const float* __restrict__ pw, const float* __restrict__ pb,
    const float* __restrict__ tw, const float* __restrict__ tb,
    float* __restrict__ out)
{
    __shared__ float s_pw[128 * 64];  // 32 KB
    __shared__ float s_tw[128 * 64];  // 32 KB
    __shared__ float s_pb[64], s_tb[64];
    __shared__ float s_in[4][128];

    for (int i = threadIdx.x; i < 128 * 64; i += 256) {
        s_pw[i] = pw[i];
        s_tw[i] = tw[i];
    }
    if (threadIdx.x < 64) {
        s_pb[threadIdx.x] = pb[threadIdx.x];
        s_tb[threadIdx.x] = tb[threadIdx.x];
    }
    __syncthreads();

    const int lane = threadIdx.x & 63;
    const int wid  = threadIdx.x >> 6;

    for (int n = blockIdx.x * 4 + wid; n < NN; n += gridDim.x * 4) {
        float h = hid[(size_t)n * 64 + lane];
        s_in[wid][lane]      = h;
        s_in[wid][64 + lane] = prev[(size_t)n * 64 + lane];

        float ap[2] = { s_pb[lane], 0.f };
        float at[2] = { s_tb[lane], 0.f };
        #pragma unroll 8
        for (int k = 0; k < 128; k += 2) {
            float2 u = *(const float2*)&s_in[wid][k];
            ap[0] = fmaf(u.x, s_pw[(k + 0) * 64 + lane], ap[0]);
            at[0] = fmaf(u.x, s_tw[(k + 0) * 64 + lane], at[0]);
            ap[1] = fmaf(u.y, s_pw[(k + 1) * 64 + lane], ap[1]);
            at[1] = fmaf(u.y, s_tw[(k + 1) * 64 + lane], at[1]);
        }
        float proj = fmaxf(ap[0] + ap[1], 0.f);
        float gate = 1.0f / (1.0f + __expf(-(at[0] + at[1])));
        out[(size_t)n * 64 + lane] = gate * proj + (1.0f - gate) * h;
    }
}

// ---------------------------------------------------------------------------
extern "C" void kernel_launch(void* const* d_in, const int* in_sizes, int n_in,
                              void* d_out, int out_size, void* d_ws, size_t ws_size,
                              hipStream_t stream)
{
    const float* node_feat = (const float*)d_in[0];
    const float* ew        = (const float*)d_in[1];
    const float* lin_w     = (const float*)d_in[2];   // [3,256,64]
    const float* lin_b     = (const float*)d_in[3];   // [3,64]
    const float* self_w    = (const float*)d_in[4];   // [3,64,64]
    const float* self_b    = (const float*)d_in[5];   // [3,64]
    const float* pw        = (const float*)d_in[6];   // [3,128,64]
    const float* pb        = (const float*)d_in[7];   // [3,64]
    const float* tw        = (const float*)d_in[8];   // [3,128,64]
    const float* tb        = (const float*)d_in[9];   // [3,64]
    const int*   src       = (const int*)d_in[10];
    const int*   dst       = (const int*)d_in[11];
    const int*   rel       = (const int*)d_in[12];
    float* out = (float*)d_out;

    char* ws = (char*)d_ws;
    float* agg  = (float*)ws;                                   // 102.4 MB
    float* deg  = (float*)(ws + AGG_BYTES);                     // 1.6 MB
    float* hidA = (float*)(ws + AGG_BYTES + DEG_BYTES);         // 25.6 MB
    float* hidB = (float*)(ws + AGG_BYTES + DEG_BYTES + FEAT_BYTES);

    const float* cur  = node_feat;
    const float* prev = node_feat;

    for (int i = 0; i < 3; ++i) {
        hipMemsetAsync(agg, 0, AGG_BYTES + DEG_BYTES, stream);
        k_scatter<<<4096, 256, 0, stream>>>(cur, ew, src, dst, rel, agg, deg);

        float* hid = (i & 1) ? hidB : hidA;
        k_conv<<<512, 256, 0, stream>>>(cur, agg, deg,
            lin_w + (size_t)i * 256 * 64, lin_b + (size_t)i * 64,
            self_w + (size_t)i * 64 * 64, self_b + (size_t)i * 64, hid);

        k_highway<<<512, 256, 0, stream>>>(hid, prev,
            pw + (size_t)i * 128 * 64, pb + (size_t)i * 64,
            tw + (size_t)i * 128 * 64, tb + (size_t)i * 64, out);

        cur  = out;
        prev = hid;
    }
}

// Round 2
// 1518.589 us; speedup vs baseline: 1.5176x; 1.5176x over previous
//
#include <hip/hip_runtime.h>

#define NN   100000
#define NE   1600000
#define NRL  4
#define DIM  64
#define EPS  1e-10f

// ---------------------------------------------------------------------------
// CSR build (once per call, reused across 3 layers)
// ---------------------------------------------------------------------------
__global__ __launch_bounds__(256) void k_hist(
    const int* __restrict__ dst, int* __restrict__ cnt)
{
    int stride = gridDim.x * blockDim.x;
    for (int e = blockIdx.x * blockDim.x + threadIdx.x; e < NE; e += stride)
        atomicAdd(&cnt[dst[e]], 1);
}

// one-block exclusive scan of cnt[NN] -> row_ptr[NN+1]
#define SCAN_T 1024
#define CHUNK  98   // ceil(100000/1024)
__global__ __launch_bounds__(SCAN_T) void k_scan(
    const int* __restrict__ cnt, int* __restrict__ row_ptr)
{
    __shared__ int s_sum[SCAN_T];
    int t = threadIdx.x;
    int beg = t * CHUNK;
    int end = min(beg + CHUNK, NN);
    int s = 0;
    for (int i = beg; i < end; ++i) s += cnt[i];
    s_sum[t] = s;
    __syncthreads();
    for (int off = 1; off < SCAN_T; off <<= 1) {
        int v = (t >= off) ? s_sum[t - off] : 0;
        __syncthreads();
        s_sum[t] += v;
        __syncthreads();
    }
    int prefix = (t == 0) ? 0 : s_sum[t - 1];
    for (int i = beg; i < end; ++i) {
        row_ptr[i] = prefix;
        prefix += cnt[i];
    }
    if (t == SCAN_T - 1) row_ptr[NN] = s_sum[SCAN_T - 1];
}

__global__ __launch_bounds__(256) void k_reorder(
    const int* __restrict__ src, const int* __restrict__ dst,
    const int* __restrict__ rel, const float* __restrict__ ew,
    int* __restrict__ cursor,
    unsigned* __restrict__ packed, float* __restrict__ wsrt)
{
    int stride = gridDim.x * blockDim.x;
    for (int e = blockIdx.x * blockDim.x + threadIdx.x; e < NE; e += stride) {
        int pos = atomicAdd(&cursor[dst[e]], 1);
        packed[pos] = (unsigned)src[e] | ((unsigned)rel[e] << 20);
        wsrt[pos]   = ew[e];
    }
}

// ---------------------------------------------------------------------------
// Fused aggregate + conv:
// hidden = sigmoid( (agg/deg) @ lin_w + lin_b + x @ self_w + self_b )
// One wave per node: walk CSR edge range, gather x[src] (lane = dim),
// per-relation register accumulators, then LDS GEMV.
// ---------------------------------------------------------------------------
__global__ __launch_bounds__(512, 4) void k_conv(
    const float* __restrict__ x,
    const int* __restrict__ row_ptr,
    const unsigned* __restrict__ packed, const float* __restrict__ wsrt,
    const float* __restrict__ lin_w, const float* __restrict__ lin_b,
    const float* __restrict__ self_w, const float* __restrict__ self_b,
    float* __restrict__ hid)
{
    __shared__ float s_w[256 * 64];   // 64 KB: lin_w
    __shared__ float s_b[64];
    __shared__ float s_in[8][320];    // per-wave: upd(256) + x(64)

    for (int i = threadIdx.x; i < 256 * 64; i += 512) s_w[i] = lin_w[i];
    if (threadIdx.x < 64)
        s_b[threadIdx.x] = lin_b[threadIdx.x] + self_b[threadIdx.x];
    __syncthreads();

    const int lane = threadIdx.x & 63;
    const int wid  = threadIdx.x >> 6;

    for (int n = blockIdx.x * 8 + wid; n < NN; n += gridDim.x * 8) {
        int beg = row_ptr[n], end = row_ptr[n + 1];

        float a0 = 0.f, a1 = 0.f, a2 = 0.f, a3 = 0.f;
        float d0 = 0.f, d1 = 0.f, d2 = 0.f, d3 = 0.f;

        int e = beg;
        for (; e + 2 <= end; e += 2) {
            unsigned p0 = packed[e], p1 = packed[e + 1];
            float w0 = wsrt[e], w1 = wsrt[e + 1];
            float m0 = x[((p0 & 0xFFFFFu) << 6) + lane] * w0;
            float m1 = x[((p1 & 0xFFFFFu) << 6) + lane] * w1;
            int r0 = p0 >> 20, r1 = p1 >> 20;
            a0 += (r0 == 0) ? m0 : 0.f;  a1 += (r0 == 1) ? m0 : 0.f;
            a2 += (r0 == 2) ? m0 : 0.f;  a3 += (r0 == 3) ? m0 : 0.f;
            d0 += (r0 == 0) ? w0 : 0.f;  d1 += (r0 == 1) ? w0 : 0.f;
            d2 += (r0 == 2) ? w0 : 0.f;  d3 += (r0 == 3) ? w0 : 0.f;
            a0 += (r1 == 0) ? m1 : 0.f;  a1 += (r1 == 1) ? m1 : 0.f;
            a2 += (r1 == 2) ? m1 : 0.f;  a3 += (r1 == 3) ? m1 : 0.f;
            d0 += (r1 == 0) ? w1 : 0.f;  d1 += (r1 == 1) ? w1 : 0.f;
            d2 += (r1 == 2) ? w1 : 0.f;  d3 += (r1 == 3) ? w1 : 0.f;
        }
        if (e < end) {
            unsigned p0 = packed[e];
            float w0 = wsrt[e];
            float m0 = x[((p0 & 0xFFFFFu) << 6) + lane] * w0;
            int r0 = p0 >> 20;
            a0 += (r0 == 0) ? m0 : 0.f;  a1 += (r0 == 1) ? m0 : 0.f;
            a2 += (r0 == 2) ? m0 : 0.f;  a3 += (r0 == 3) ? m0 : 0.f;
            d0 += (r0 == 0) ? w0 : 0.f;  d1 += (r0 == 1) ? w0 : 0.f;
            d2 += (r0 == 2) ? w0 : 0.f;  d3 += (r0 == 3) ? w0 : 0.f;
        }

        // stage upd + x for this node into the wave's LDS slot (wave-private)
        s_in[wid][0 * 64 + lane] = a0 / (d0 + EPS);
        s_in[wid][1 * 64 + lane] = a1 / (d1 + EPS);
        s_in[wid][2 * 64 + lane] = a2 / (d2 + EPS);
        s_in[wid][3 * 64 + lane] = a3 / (d3 + EPS);
        s_in[wid][256 + lane]    = x[(size_t)n * 64 + lane];

        float acc[4] = { s_b[lane], 0.f, 0.f, 0.f };

        // upd @ lin_w   (K = 256, LDS weights)
        #pragma unroll 8
        for (int k = 0; k < 256; k += 4) {
            float4 u = *(const float4*)&s_in[wid][k];
            acc[0] = fmaf(u.x, s_w[(k + 0) * 64 + lane], acc[0]);
            acc[1] = fmaf(u.y, s_w[(k + 1) * 64 + lane], acc[1]);
            acc[2] = fmaf(u.z, s_w[(k + 2) * 64 + lane], acc[2]);
            acc[3] = fmaf(u.w, s_w[(k + 3) * 64 + lane], acc[3]);
        }
        // x @ self_w    (K = 64, global weights, 16 KB -> L1-resident)
        #pragma unroll 4
        for (int k = 0; k < 64; k += 4) {
            float4 u = *(const float4*)&s_in[wid][256 + k];
            acc[0] = fmaf(u.x, self_w[(k + 0) * 64 + lane], acc[0]);
            acc[1] = fmaf(u.y, self_w[(k + 1) * 64 + lane], acc[1]);
            acc[2] = fmaf(u.z, self_w[(k + 2) * 64 + lane], acc[2]);
            acc[3] = fmaf(u.w, self_w[(k + 3) * 64 + lane], acc[3]);
        }
        float o = (acc[0] + acc[1]) + (acc[2] + acc[3]);
        hid[(size_t)n * 64 + lane] = 1.0f / (1.0f + __expf(-o));
    }
}

// ---------------------------------------------------------------------------
// Highway: cat = [hid, prev];
// proj = relu(cat@pw + pb); gate = sigmoid(cat@tw + tb);
// out = gate*proj + (1-gate)*hid
// ---------------------------------------------------------------------------
__global__ __launch_bounds__(256, 2) void k_highway(
    const float* __restrict__ hid, const float* __restrict__ prev,
    const float* __restrict__ pw, const float* __restrict__ pb,
    const float* __restrict__ tw, const float* __restrict__ tb,
    float* __restrict__ out)
{
    __shared__ float s_pw[128 * 64];  // 32 KB
    __shared__ float s_tw[128 * 64];  // 32 KB
    __shared__ float s_pb[64], s_tb[64];
    __shared__ float s_in[4][128];

    for (int i = threadIdx.x; i < 128 * 64; i += 256) {
        s_pw[i] = pw[i];
        s_tw[i] = tw[i];
    }
    if (threadIdx.x < 64) {
        s_pb[threadIdx.x] = pb[threadIdx.x];
        s_tb[threadIdx.x] = tb[threadIdx.x];
    }
    __syncthreads();

    const int lane = threadIdx.x & 63;
    const int wid  = threadIdx.x >> 6;

    for (int n = blockIdx.x * 4 + wid; n < NN; n += gridDim.x * 4) {
        float h = hid[(size_t)n * 64 + lane];
        s_in[wid][lane]      = h;
        s_in[wid][64 + lane] = prev[(size_t)n * 64 + lane];

        float ap[2] = { s_pb[lane], 0.f };
        float at[2] = { s_tb[lane], 0.f };
        #pragma unroll 8
        for (int k = 0; k < 128; k += 2) {
            float2 u = *(const float2*)&s_in[wid][k];
            ap[0] = fmaf(u.x, s_pw[(k + 0) * 64 + lane], ap[0]);
            at[0] = fmaf(u.x, s_tw[(k + 0) * 64 + lane], at[0]);
            ap[1] = fmaf(u.y, s_pw[(k + 1) * 64 + lane], ap[1]);
            at[1] = fmaf(u.y, s_tw[(k + 1) * 64 + lane], at[1]);
        }
        float proj = fmaxf(ap[0] + ap[1], 0.f);
        float gate = 1.0f / (1.0f + __expf(-(at[0] + at[1])));
        out[(size_t)n * 64 + lane] = gate * proj + (1.0f - gate) * h;
    }
}

// ---------------------------------------------------------------------------
extern "C" void kernel_launch(void* const* d_in, const int* in_sizes, int n_in,
                              void* d_out, int out_size, void* d_ws, size_t ws_size,
                              hipStream_t stream)
{
    const float* node_feat = (const float*)d_in[0];
    const float* ew        = (const float*)d_in[1];
    const float* lin_w     = (const float*)d_in[2];   // [3,256,64]
    const float* lin_b     = (const float*)d_in[3];   // [3,64]
    const float* self_w    = (const float*)d_in[4];   // [3,64,64]
    const float* self_b    = (const float*)d_in[5];   // [3,64]
    const float* pw        = (const float*)d_in[6];   // [3,128,64]
    const float* pb        = (const float*)d_in[7];   // [3,64]
    const float* tw        = (const float*)d_in[8];   // [3,128,64]
    const float* tb        = (const float*)d_in[9];   // [3,64]
    const int*   src       = (const int*)d_in[10];
    const int*   dst       = (const int*)d_in[11];
    const int*   rel       = (const int*)d_in[12];
    float* out = (float*)d_out;

    // workspace layout
    char* ws = (char*)d_ws;
    int*      row_ptr = (int*)ws;                       //  (NN+1)*4
    int*      cnt     = (int*)(ws + 400128);            //  NN*4
    int*      cursor  = (int*)(ws + 800128);            //  NN*4
    unsigned* packed  = (unsigned*)(ws + 1200128);      //  NE*4
    float*    wsrt    = (float*)(ws + 1200128 + 6400000);
    float*    hidA    = (float*)(ws + 1200128 + 12800000);
    float*    hidB    = (float*)(ws + 1200128 + 12800000 + 25600000);

    // ---- CSR build (edge structure is layer-invariant) ----
    hipMemsetAsync(cnt, 0, NN * sizeof(int), stream);
    k_hist<<<2048, 256, 0, stream>>>(dst, cnt);
    k_scan<<<1, SCAN_T, 0, stream>>>(cnt, row_ptr);
    hipMemcpyAsync(cursor, row_ptr, NN * sizeof(int),
                   hipMemcpyDeviceToDevice, stream);
    k_reorder<<<2048, 256, 0, stream>>>(src, dst, rel, ew, cursor, packed, wsrt);

    const float* cur  = node_feat;
    const float* prev = node_feat;

    for (int i = 0; i < 3; ++i) {
        float* hid = (i & 1) ? hidB : hidA;
        k_conv<<<512, 512, 0, stream>>>(cur, row_ptr, packed, wsrt,
            lin_w + (size_t)i * 256 * 64, lin_b + (size_t)i * 64,
            self_w + (size_t)i * 64 * 64, self_b + (size_t)i * 64, hid);

        k_highway<<<512, 256, 0, stream>>>(hid, prev,
            pw + (size_t)i * 128 * 64, pb + (size_t)i * 64,
            tw + (size_t)i * 128 * 64, tb + (size_t)i * 64, out);

        cur  = out;
        prev = hid;
    }
}

// Round 3
// 1494.911 us; speedup vs baseline: 1.5416x; 1.0158x over previous
//
#include <hip/hip_runtime.h>

#define NN   100000
#define NE   1600000
#define NB   400000     // NN*4 (dst,rel) segments
#define EPS  1e-10f

typedef __attribute__((ext_vector_type(8))) short bfrag8;
typedef __attribute__((ext_vector_type(4))) float f4acc;

__device__ __forceinline__ unsigned short f2bf(float f) {
    union { float f; unsigned u; } v; v.f = f;
    unsigned r = v.u + 0x7FFF + ((v.u >> 16) & 1);
    return (unsigned short)(r >> 16);
}
__device__ __forceinline__ float bf2f(unsigned short b) {
    union { unsigned u; float f; } v; v.u = ((unsigned)b) << 16;
    return v.f;
}

// ---------------------------------------------------------------------------
// CSR build: key = dst*4 + rel  (400K segments)
// ---------------------------------------------------------------------------
__global__ __launch_bounds__(256) void k_hist(
    const int* __restrict__ dst, const int* __restrict__ rel,
    int* __restrict__ cnt)
{
    int stride = gridDim.x * blockDim.x;
    for (int e = blockIdx.x * blockDim.x + threadIdx.x; e < NE; e += stride)
        atomicAdd(&cnt[dst[e] * 4 + rel[e]], 1);
}

#define SCAN_T 1024
#define CHUNK  391   // ceil(400000/1024)
__global__ __launch_bounds__(SCAN_T) void k_scan(
    const int* __restrict__ cnt, int* __restrict__ row_ptr)
{
    __shared__ int s_sum[SCAN_T];
    int t = threadIdx.x;
    int beg = t * CHUNK;
    int end = min(beg + CHUNK, NB);
    int s = 0;
    for (int i = beg; i < end; ++i) s += cnt[i];
    s_sum[t] = s;
    __syncthreads();
    for (int off = 1; off < SCAN_T; off <<= 1) {
        int v = (t >= off) ? s_sum[t - off] : 0;
        __syncthreads();
        s_sum[t] += v;
        __syncthreads();
    }
    int prefix = (t == 0) ? 0 : s_sum[t - 1];
    for (int i = beg; i < end; ++i) {
        row_ptr[i] = prefix;
        prefix += cnt[i];
    }
    if (t == SCAN_T - 1) row_ptr[NB] = s_sum[SCAN_T - 1];
}

__global__ __launch_bounds__(256) void k_reorder(
    const int* __restrict__ src, const int* __restrict__ dst,
    const int* __restrict__ rel, const float* __restrict__ ew,
    int* __restrict__ cursor, int2* __restrict__ edat)
{
    int stride = gridDim.x * blockDim.x;
    for (int e = blockIdx.x * blockDim.x + threadIdx.x; e < NE; e += stride) {
        int pos = atomicAdd(&cursor[dst[e] * 4 + rel[e]], 1);
        int2 v; v.x = src[e]; v.y = __float_as_int(ew[e]);
        edat[pos] = v;
    }
}

// ---------------------------------------------------------------------------
// Conversions: node features -> bf16; weights -> transposed bf16
// WL[64][320] (lin_w^T | self_w^T), WP/WT2[64][128]
// ---------------------------------------------------------------------------
__global__ __launch_bounds__(256) void k_cvt_x(
    const float* __restrict__ xf, unsigned short* __restrict__ xb)
{
    int i = blockIdx.x * 256 + threadIdx.x;
    if (i < NN * 64) xb[i] = f2bf(xf[i]);
}

__global__ __launch_bounds__(256) void k_cvt_w(
    const float* __restrict__ lin_w, const float* __restrict__ self_w,
    const float* __restrict__ pw, const float* __restrict__ tw,
    unsigned short* __restrict__ WL, unsigned short* __restrict__ WP,
    unsigned short* __restrict__ WT2)
{
    int id = blockIdx.x * 256 + threadIdx.x;   // 3*64*576
    if (id >= 3 * 64 * 576) return;
    int i = id / (64 * 576);
    int r = id % (64 * 576);
    int j = r / 576;
    int k = r % 576;
    if (k < 320) {
        float v = (k < 256) ? lin_w[((size_t)i * 256 + k) * 64 + j]
                            : self_w[((size_t)i * 64 + (k - 256)) * 64 + j];
        WL[((size_t)i * 64 + j) * 320 + k] = f2bf(v);
    } else if (k < 448) {
        int kk = k - 320;
        WP[((size_t)i * 64 + j) * 128 + kk] = f2bf(pw[((size_t)i * 128 + kk) * 64 + j]);
    } else {
        int kk = k - 448;
        WT2[((size_t)i * 64 + j) * 128 + kk] = f2bf(tw[((size_t)i * 128 + kk) * 64 + j]);
    }
}

// ---------------------------------------------------------------------------
// Fused layer: edge-aggregate -> conv MFMA -> sigmoid -> highway MFMA -> gated
// block = 256 threads = 4 waves, 16 nodes per block (4 per wave).
// LDS A-tile [16][320] bf16 + H-tile [16][128] bf16, XOR-swizzled rows.
// ---------------------------------------------------------------------------
__global__ __launch_bounds__(256) void k_layer(
    const unsigned short* __restrict__ xb,     // layer input bf16 [NN][64]
    const unsigned short* __restrict__ prevb,  // prev hidden bf16 [NN][64]
    const int* __restrict__ row_ptr,
    const int2* __restrict__ edat,
    const unsigned short* __restrict__ WL,     // [64][320]
    const unsigned short* __restrict__ WP,     // [64][128]
    const unsigned short* __restrict__ WT2,    // [64][128]
    const float* __restrict__ lin_b, const float* __restrict__ self_b,
    const float* __restrict__ pb, const float* __restrict__ tb,
    unsigned short* __restrict__ hidb,         // hidden bf16 out
    unsigned short* __restrict__ gatedb,       // gated bf16 out (non-last)
    float* __restrict__ outf,                  // gated f32 out (last)
    int last)
{
    __shared__ __align__(16) unsigned short sA[16 * 320];  // 10240 B
    __shared__ __align__(16) unsigned short sH[16 * 128];  //  4096 B

    const int tid  = threadIdx.x;
    const int lane = tid & 63;
    const int wid  = tid >> 6;
    const int n0   = blockIdx.x * 16;
    const int bcol = wid * 16 + (lane & 15);        // output column
    const int koff2 = (lane >> 4) * 16;             // byte offset of 8-elem k group
    const int arow = lane & 15;

    // ---- prev staging into sH cols 64..127 (whole block) ----
    #pragma unroll
    for (int j = 0; j < 4; ++j) {
        int idx = tid + 256 * j;                    // 0..1023
        int row = idx >> 6, col = idx & 63;
        int cb = (64 + col) * 2;
        *(unsigned short*)((char*)sH + row * 256 + (cb ^ ((row & 7) << 4))) =
            prevb[(size_t)(n0 + row) * 64 + col];
    }
    // ---- x rows into sA cols 256..319 (wave's 4 nodes) ----
    #pragma unroll
    for (int j = 0; j < 4; ++j) {
        int ln = wid * 4 + j;
        int cb = (256 + lane) * 2;
        *(unsigned short*)((char*)sA + ln * 640 + (cb ^ ((ln & 7) << 4))) =
            xb[(size_t)(n0 + ln) * 64 + lane];
    }

    // ---- edge aggregation over the wave's 16 contiguous segments ----
    int s0 = (n0 + wid * 4) * 4;
    int E0 = row_ptr[s0];
    int E1 = row_ptr[s0 + 16];
    int seg = 0;
    int segEnd = row_ptr[s0 + 1];
    float acc = 0.f, dsum = 0.f;

    int sN = 0; float wN = 0.f;
    unsigned short xcur = 0; float wcur = 0.f;
    if (E0 < E1) {
        int2 m = edat[E0];
        sN = m.x; wN = __int_as_float(m.y);
        xcur = xb[(sN << 6) + lane]; wcur = wN;
        if (E0 + 1 < E1) {
            int2 m2 = edat[E0 + 1];
            sN = m2.x; wN = __int_as_float(m2.y);
        }
    }
    for (int e = E0; e < E1; ++e) {
        unsigned short xnxt = 0; float wnxt = 0.f;
        if (e + 1 < E1) {
            xnxt = xb[(sN << 6) + lane]; wnxt = wN;   // gather e+1 (addr prefetched)
            if (e + 2 < E1) {
                int2 m = edat[e + 2];
                sN = m.x; wN = __int_as_float(m.y);
            }
        }
        while (e >= segEnd) {                          // flush completed segments
            float u = acc / (dsum + EPS);
            int ln = wid * 4 + (seg >> 2);
            int cb = ((seg & 3) * 64 + lane) * 2;
            *(unsigned short*)((char*)sA + ln * 640 + (cb ^ ((ln & 7) << 4))) = f2bf(u);
            acc = 0.f; dsum = 0.f;
            ++seg; segEnd = row_ptr[s0 + seg + 1];
        }
        acc = fmaf(bf2f(xcur), wcur, acc);
        dsum += wcur;
        xcur = xnxt; wcur = wnxt;
    }
    while (seg < 16) {                                 // trailing flush
        float u = acc / (dsum + EPS);
        int ln = wid * 4 + (seg >> 2);
        int cb = ((seg & 3) * 64 + lane) * 2;
        *(unsigned short*)((char*)sA + ln * 640 + (cb ^ ((ln & 7) << 4))) = f2bf(u);
        acc = 0.f; dsum = 0.f;
        ++seg;
    }

    // ---- conv B-fragments (issued before barrier; latency hides in barrier) ----
    bfrag8 bwL[10];
    #pragma unroll
    for (int ks = 0; ks < 10; ++ks)
        bwL[ks] = *(const bfrag8*)((const char*)WL + bcol * 640 + ks * 64 + koff2);
    float biasC = lin_b[bcol] + self_b[bcol];
    float pbv = pb[bcol], tbv = tb[bcol];

    __syncthreads();

    // ---- conv MFMA: wave computes cols [wid*16, wid*16+16), K = 320 ----
    f4acc accC = {0.f, 0.f, 0.f, 0.f};
    #pragma unroll
    for (int ks = 0; ks < 10; ++ks) {
        bfrag8 a = *(const bfrag8*)((const char*)sA + arow * 640 +
                                    ((ks * 64 + koff2) ^ ((arow & 7) << 4)));
        accC = __builtin_amdgcn_mfma_f32_16x16x32_bf16(a, bwL[ks], accC, 0, 0, 0);
    }

    // highway B-fragments
    bfrag8 bwP[4], bwT[4];
    #pragma unroll
    for (int ks = 0; ks < 4; ++ks) {
        bwP[ks] = *(const bfrag8*)((const char*)WP  + bcol * 256 + ks * 64 + koff2);
        bwT[ks] = *(const bfrag8*)((const char*)WT2 + bcol * 256 + ks * 64 + koff2);
    }

    // sigmoid epilogue; stage hid into sH cols 0..63; store hidden bf16
    float hid[4];
    #pragma unroll
    for (int q = 0; q < 4; ++q) {
        float o = accC[q] + biasC;
        hid[q] = 1.f / (1.f + __expf(-o));
        int row = (lane >> 4) * 4 + q;
        unsigned short hb = f2bf(hid[q]);
        *(unsigned short*)((char*)sH + row * 256 + ((bcol * 2) ^ ((row & 7) << 4))) = hb;
        hidb[(size_t)(n0 + row) * 64 + bcol] = hb;
    }

    __syncthreads();

    // ---- highway MFMA: cat=[hid, prev], K = 128 ----
    f4acc accP = {0.f, 0.f, 0.f, 0.f};
    f4acc accT = {0.f, 0.f, 0.f, 0.f};
    #pragma unroll
    for (int ks = 0; ks < 4; ++ks) {
        bfrag8 a = *(const bfrag8*)((const char*)sH + arow * 256 +
                                    ((ks * 64 + koff2) ^ ((arow & 7) << 4)));
        accP = __builtin_amdgcn_mfma_f32_16x16x32_bf16(a, bwP[ks], accP, 0, 0, 0);
        accT = __builtin_amdgcn_mfma_f32_16x16x32_bf16(a, bwT[ks], accT, 0, 0, 0);
    }

    #pragma unroll
    for (int q = 0; q < 4; ++q) {
        float proj = fmaxf(accP[q] + pbv, 0.f);
        float gate = 1.f / (1.f + __expf(-(accT[q] + tbv)));
        float o = gate * proj + (1.f - gate) * hid[q];
        int row = (lane >> 4) * 4 + q;
        if (last) outf[(size_t)(n0 + row) * 64 + bcol] = o;
        else      gatedb[(size_t)(n0 + row) * 64 + bcol] = f2bf(o);
    }
}

// ---------------------------------------------------------------------------
extern "C" void kernel_launch(void* const* d_in, const int* in_sizes, int n_in,
                              void* d_out, int out_size, void* d_ws, size_t ws_size,
                              hipStream_t stream)
{
    const float* node_feat = (const float*)d_in[0];
    const float* ew        = (const float*)d_in[1];
    const float* lin_w     = (const float*)d_in[2];
    const float* lin_b     = (const float*)d_in[3];
    const float* self_w    = (const float*)d_in[4];
    const float* self_b    = (const float*)d_in[5];
    const float* pw        = (const float*)d_in[6];
    const float* pb        = (const float*)d_in[7];
    const float* tw        = (const float*)d_in[8];
    const float* tb        = (const float*)d_in[9];
    const int*   src       = (const int*)d_in[10];
    const int*   dst       = (const int*)d_in[11];
    const int*   rel       = (const int*)d_in[12];
    float* outf = (float*)d_out;

    char* ws = (char*)d_ws;
    int*            row_ptr = (int*)(ws + 0);                 // (NB+1)*4 + slack
    int*            cnt     = (int*)(ws + 1600256);
    int*            cursor  = (int*)(ws + 3200256);
    int2*           edat    = (int2*)(ws + 4800256);          // 12.8 MB
    unsigned short* nfb     = (unsigned short*)(ws + 17600256);
    unsigned short* hbfA    = (unsigned short*)(ws + 30400256);
    unsigned short* hbfB    = (unsigned short*)(ws + 43200256);
    unsigned short* gbfA    = (unsigned short*)(ws + 56000256);
    unsigned short* gbfB    = (unsigned short*)(ws + 68800256);
    unsigned short* WL      = (unsigned short*)(ws + 81600256);   // 3*64*320
    unsigned short* WP      = (unsigned short*)(ws + 81600256 + 122880);
    unsigned short* WT2     = (unsigned short*)(ws + 81600256 + 122880 + 49152);

    // CSR build (layer-invariant)
    hipMemsetAsync(cnt, 0, NB * sizeof(int), stream);
    k_hist<<<2048, 256, 0, stream>>>(dst, rel, cnt);
    k_scan<<<1, SCAN_T, 0, stream>>>(cnt, row_ptr);
    hipMemcpyAsync(cursor, row_ptr, NB * sizeof(int),
                   hipMemcpyDeviceToDevice, stream);
    k_reorder<<<2048, 256, 0, stream>>>(src, dst, rel, ew, cursor, edat);

    // bf16 conversions
    k_cvt_x<<<25000, 256, 0, stream>>>(node_feat, nfb);
    k_cvt_w<<<432, 256, 0, stream>>>(lin_w, self_w, pw, tw, WL, WP, WT2);

    const unsigned short* cur  = nfb;
    const unsigned short* prev = nfb;
    unsigned short* hbuf[3] = { hbfA, hbfB, hbfA };
    unsigned short* gbuf[3] = { gbfA, gbfB, gbfA };

    for (int i = 0; i < 3; ++i) {
        int lastL = (i == 2);
        k_layer<<<NN / 16, 256, 0, stream>>>(
            cur, prev, row_ptr, edat,
            WL  + (size_t)i * 64 * 320,
            WP  + (size_t)i * 64 * 128,
            WT2 + (size_t)i * 64 * 128,
            lin_b + (size_t)i * 64, self_b + (size_t)i * 64,
            pb + (size_t)i * 64, tb + (size_t)i * 64,
            hbuf[i], gbuf[i], outf, lastL);
        cur  = gbuf[i];
        prev = hbuf[i];
    }
}

// Round 4
// 840.512 us; speedup vs baseline: 2.7419x; 1.7786x over previous
//
#include <hip/hip_runtime.h>

#define NN   100000
#define NE   1600000
#define NB   400000     // NN*4 (dst,rel) segments
#define EPS  1e-10f

#define NBLK_SCAN 391   // ceil(NB/1024)

typedef __attribute__((ext_vector_type(8))) short bfrag8;
typedef __attribute__((ext_vector_type(4))) float f4acc;

__device__ __forceinline__ unsigned short f2bf(float f) {
    union { float f; unsigned u; } v; v.f = f;
    unsigned r = v.u + 0x7FFF + ((v.u >> 16) & 1);
    return (unsigned short)(r >> 16);
}
__device__ __forceinline__ float bf2f(unsigned short b) {
    union { unsigned u; float f; } v; v.u = ((unsigned)b) << 16;
    return v.f;
}

// ---------------------------------------------------------------------------
// CSR build: key = dst*4 + rel  (400K segments)
// ---------------------------------------------------------------------------
__global__ __launch_bounds__(256) void k_hist(
    const int* __restrict__ dst, const int* __restrict__ rel,
    int* __restrict__ cnt)
{
    int stride = gridDim.x * blockDim.x;
    for (int e = blockIdx.x * blockDim.x + threadIdx.x; e < NE; e += stride)
        atomicAdd(&cnt[dst[e] * 4 + rel[e]], 1);
}

// --- coalesced 3-phase scan ------------------------------------------------
// phase 1: per-block (1024 elems) local exclusive scan -> row_ptr, total -> blksum
__global__ __launch_bounds__(1024) void k_scan_local(
    const int* __restrict__ cnt, int* __restrict__ row_ptr,
    int* __restrict__ blksum)
{
    __shared__ int s[1024];
    int t = threadIdx.x;
    int i = blockIdx.x * 1024 + t;
    int v = (i < NB) ? cnt[i] : 0;
    s[t] = v;
    __syncthreads();
    #pragma unroll
    for (int off = 1; off < 1024; off <<= 1) {
        int u = (t >= off) ? s[t - off] : 0;
        __syncthreads();
        s[t] += u;
        __syncthreads();
    }
    if (i < NB) row_ptr[i] = s[t] - v;          // local exclusive
    if (t == 1023) blksum[blockIdx.x] = s[t];
}

// phase 2: scan the 391 block sums (one block), write grand total to row_ptr[NB]
__global__ __launch_bounds__(512) void k_scan_blk(
    int* __restrict__ blksum, int* __restrict__ blkoff, int* __restrict__ row_ptr)
{
    __shared__ int s[512];
    int t = threadIdx.x;
    int v = (t < NBLK_SCAN) ? blksum[t] : 0;
    s[t] = v;
    __syncthreads();
    #pragma unroll
    for (int off = 1; off < 512; off <<= 1) {
        int u = (t >= off) ? s[t - off] : 0;
        __syncthreads();
        s[t] += u;
        __syncthreads();
    }
    if (t < NBLK_SCAN) blkoff[t] = s[t] - v;    // exclusive block offsets
    if (t == NBLK_SCAN - 1) row_ptr[NB] = s[t];
}

// phase 3: add block offset in place; also emit cursor copy
__global__ __launch_bounds__(1024) void k_scan_add(
    int* __restrict__ row_ptr, const int* __restrict__ blkoff,
    int* __restrict__ cursor)
{
    int i = blockIdx.x * 1024 + threadIdx.x;
    if (i < NB) {
        int v = row_ptr[i] + blkoff[blockIdx.x];
        row_ptr[i] = v;
        cursor[i] = v;
    }
}

__global__ __launch_bounds__(256) void k_reorder(
    const int* __restrict__ src, const int* __restrict__ dst,
    const int* __restrict__ rel, const float* __restrict__ ew,
    int* __restrict__ cursor, int2* __restrict__ edat)
{
    int stride = gridDim.x * blockDim.x;
    for (int e = blockIdx.x * blockDim.x + threadIdx.x; e < NE; e += stride) {
        int pos = atomicAdd(&cursor[dst[e] * 4 + rel[e]], 1);
        int2 v; v.x = src[e]; v.y = __float_as_int(ew[e]);
        edat[pos] = v;
    }
}

// ---------------------------------------------------------------------------
// Conversions: node features -> bf16; weights -> transposed bf16
// WL[64][320] (lin_w^T | self_w^T), WP/WT2[64][128]
// ---------------------------------------------------------------------------
__global__ __launch_bounds__(256) void k_cvt_x(
    const float* __restrict__ xf, unsigned short* __restrict__ xb)
{
    int i = blockIdx.x * 256 + threadIdx.x;
    if (i < NN * 64) xb[i] = f2bf(xf[i]);
}

__global__ __launch_bounds__(256) void k_cvt_w(
    const float* __restrict__ lin_w, const float* __restrict__ self_w,
    const float* __restrict__ pw, const float* __restrict__ tw,
    unsigned short* __restrict__ WL, unsigned short* __restrict__ WP,
    unsigned short* __restrict__ WT2)
{
    int id = blockIdx.x * 256 + threadIdx.x;   // 3*64*576
    if (id >= 3 * 64 * 576) return;
    int i = id / (64 * 576);
    int r = id % (64 * 576);
    int j = r / 576;
    int k = r % 576;
    if (k < 320) {
        float v = (k < 256) ? lin_w[((size_t)i * 256 + k) * 64 + j]
                            : self_w[((size_t)i * 64 + (k - 256)) * 64 + j];
        WL[((size_t)i * 64 + j) * 320 + k] = f2bf(v);
    } else if (k < 448) {
        int kk = k - 320;
        WP[((size_t)i * 64 + j) * 128 + kk] = f2bf(pw[((size_t)i * 128 + kk) * 64 + j]);
    } else {
        int kk = k - 448;
        WT2[((size_t)i * 64 + j) * 128 + kk] = f2bf(tw[((size_t)i * 128 + kk) * 64 + j]);
    }
}

// ---------------------------------------------------------------------------
// Fused layer: edge-aggregate -> conv MFMA -> sigmoid -> highway MFMA -> gated
// block = 256 threads = 4 waves, 16 nodes per block (4 per wave).
// LDS A-tile [16][320] bf16 + H-tile [16][128] bf16, XOR-swizzled rows.
// ---------------------------------------------------------------------------
__global__ __launch_bounds__(256) void k_layer(
    const unsigned short* __restrict__ xb,     // layer input bf16 [NN][64]
    const unsigned short* __restrict__ prevb,  // prev hidden bf16 [NN][64]
    const int* __restrict__ row_ptr,
    const int2* __restrict__ edat,
    const unsigned short* __restrict__ WL,     // [64][320]
    const unsigned short* __restrict__ WP,     // [64][128]
    const unsigned short* __restrict__ WT2,    // [64][128]
    const float* __restrict__ lin_b, const float* __restrict__ self_b,
    const float* __restrict__ pb, const float* __restrict__ tb,
    unsigned short* __restrict__ hidb,         // hidden bf16 out
    unsigned short* __restrict__ gatedb,       // gated bf16 out (non-last)
    float* __restrict__ outf,                  // gated f32 out (last)
    int last)
{
    __shared__ __align__(16) unsigned short sA[16 * 320];  // 10240 B
    __shared__ __align__(16) unsigned short sH[16 * 128];  //  4096 B

    const int tid  = threadIdx.x;
    const int lane = tid & 63;
    const int wid  = tid >> 6;
    const int n0   = blockIdx.x * 16;
    const int bcol = wid * 16 + (lane & 15);        // output column
    const int koff2 = (lane >> 4) * 16;             // byte offset of 8-elem k group
    const int arow = lane & 15;

    // ---- prev staging into sH cols 64..127 (whole block) ----
    #pragma unroll
    for (int j = 0; j < 4; ++j) {
        int idx = tid + 256 * j;                    // 0..1023
        int row = idx >> 6, col = idx & 63;
        int cb = (64 + col) * 2;
        *(unsigned short*)((char*)sH + row * 256 + (cb ^ ((row & 7) << 4))) =
            prevb[(size_t)(n0 + row) * 64 + col];
    }
    // ---- x rows into sA cols 256..319 (wave's 4 nodes) ----
    #pragma unroll
    for (int j = 0; j < 4; ++j) {
        int ln = wid * 4 + j;
        int cb = (256 + lane) * 2;
        *(unsigned short*)((char*)sA + ln * 640 + (cb ^ ((ln & 7) << 4))) =
            xb[(size_t)(n0 + ln) * 64 + lane];
    }

    // ---- edge aggregation over the wave's 16 contiguous segments ----
    int s0 = (n0 + wid * 4) * 4;
    int E0 = row_ptr[s0];
    int E1 = row_ptr[s0 + 16];
    int seg = 0;
    int segEnd = row_ptr[s0 + 1];
    float acc = 0.f, dsum = 0.f;

    int sN = 0; float wN = 0.f;
    unsigned short xcur = 0; float wcur = 0.f;
    if (E0 < E1) {
        int2 m = edat[E0];
        sN = m.x; wN = __int_as_float(m.y);
        xcur = xb[(sN << 6) + lane]; wcur = wN;
        if (E0 + 1 < E1) {
            int2 m2 = edat[E0 + 1];
            sN = m2.x; wN = __int_as_float(m2.y);
        }
    }
    for (int e = E0; e < E1; ++e) {
        unsigned short xnxt = 0; float wnxt = 0.f;
        if (e + 1 < E1) {
            xnxt = xb[(sN << 6) + lane]; wnxt = wN;   // gather e+1 (addr prefetched)
            if (e + 2 < E1) {
                int2 m = edat[e + 2];
                sN = m.x; wN = __int_as_float(m.y);
            }
        }
        while (e >= segEnd) {                          // flush completed segments
            float u = acc / (dsum + EPS);
            int ln = wid * 4 + (seg >> 2);
            int cb = ((seg & 3) * 64 + lane) * 2;
            *(unsigned short*)((char*)sA + ln * 640 + (cb ^ ((ln & 7) << 4))) = f2bf(u);
            acc = 0.f; dsum = 0.f;
            ++seg; segEnd = row_ptr[s0 + seg + 1];
        }
        acc = fmaf(bf2f(xcur), wcur, acc);
        dsum += wcur;
        xcur = xnxt; wcur = wnxt;
    }
    while (seg < 16) {                                 // trailing flush
        float u = acc / (dsum + EPS);
        int ln = wid * 4 + (seg >> 2);
        int cb = ((seg & 3) * 64 + lane) * 2;
        *(unsigned short*)((char*)sA + ln * 640 + (cb ^ ((ln & 7) << 4))) = f2bf(u);
        acc = 0.f; dsum = 0.f;
        ++seg;
    }

    // ---- conv B-fragments (issued before barrier; latency hides in barrier) ----
    bfrag8 bwL[10];
    #pragma unroll
    for (int ks = 0; ks < 10; ++ks)
        bwL[ks] = *(const bfrag8*)((const char*)WL + bcol * 640 + ks * 64 + koff2);
    float biasC = lin_b[bcol] + self_b[bcol];
    float pbv = pb[bcol], tbv = tb[bcol];

    __syncthreads();

    // ---- conv MFMA: wave computes cols [wid*16, wid*16+16), K = 320 ----
    f4acc accC = {0.f, 0.f, 0.f, 0.f};
    #pragma unroll
    for (int ks = 0; ks < 10; ++ks) {
        bfrag8 a = *(const bfrag8*)((const char*)sA + arow * 640 +
                                    ((ks * 64 + koff2) ^ ((arow & 7) << 4)));
        accC = __builtin_amdgcn_mfma_f32_16x16x32_bf16(a, bwL[ks], accC, 0, 0, 0);
    }

    // highway B-fragments
    bfrag8 bwP[4], bwT[4];
    #pragma unroll
    for (int ks = 0; ks < 4; ++ks) {
        bwP[ks] = *(const bfrag8*)((const char*)WP  + bcol * 256 + ks * 64 + koff2);
        bwT[ks] = *(const bfrag8*)((const char*)WT2 + bcol * 256 + ks * 64 + koff2);
    }

    // sigmoid epilogue; stage hid into sH cols 0..63; store hidden bf16
    float hid[4];
    #pragma unroll
    for (int q = 0; q < 4; ++q) {
        float o = accC[q] + biasC;
        hid[q] = 1.f / (1.f + __expf(-o));
        int row = (lane >> 4) * 4 + q;
        unsigned short hb = f2bf(hid[q]);
        *(unsigned short*)((char*)sH + row * 256 + ((bcol * 2) ^ ((row & 7) << 4))) = hb;
        hidb[(size_t)(n0 + row) * 64 + bcol] = hb;
    }

    __syncthreads();

    // ---- highway MFMA: cat=[hid, prev], K = 128 ----
    f4acc accP = {0.f, 0.f, 0.f, 0.f};
    f4acc accT = {0.f, 0.f, 0.f, 0.f};
    #pragma unroll
    for (int ks = 0; ks < 4; ++ks) {
        bfrag8 a = *(const bfrag8*)((const char*)sH + arow * 256 +
                                    ((ks * 64 + koff2) ^ ((arow & 7) << 4)));
        accP = __builtin_amdgcn_mfma_f32_16x16x32_bf16(a, bwP[ks], accP, 0, 0, 0);
        accT = __builtin_amdgcn_mfma_f32_16x16x32_bf16(a, bwT[ks], accT, 0, 0, 0);
    }

    #pragma unroll
    for (int q = 0; q < 4; ++q) {
        float proj = fmaxf(accP[q] + pbv, 0.f);
        float gate = 1.f / (1.f + __expf(-(accT[q] + tbv)));
        float o = gate * proj + (1.f - gate) * hid[q];
        int row = (lane >> 4) * 4 + q;
        if (last) outf[(size_t)(n0 + row) * 64 + bcol] = o;
        else      gatedb[(size_t)(n0 + row) * 64 + bcol] = f2bf(o);
    }
}

// ---------------------------------------------------------------------------
extern "C" void kernel_launch(void* const* d_in, const int* in_sizes, int n_in,
                              void* d_out, int out_size, void* d_ws, size_t ws_size,
                              hipStream_t stream)
{
    const float* node_feat = (const float*)d_in[0];
    const float* ew        = (const float*)d_in[1];
    const float* lin_w     = (const float*)d_in[2];
    const float* lin_b     = (const float*)d_in[3];
    const float* self_w    = (const float*)d_in[4];
    const float* self_b    = (const float*)d_in[5];
    const float* pw        = (const float*)d_in[6];
    const float* pb        = (const float*)d_in[7];
    const float* tw        = (const float*)d_in[8];
    const float* tb        = (const float*)d_in[9];
    const int*   src       = (const int*)d_in[10];
    const int*   dst       = (const int*)d_in[11];
    const int*   rel       = (const int*)d_in[12];
    float* outf = (float*)d_out;

    char* ws = (char*)d_ws;
    int*            row_ptr = (int*)(ws + 0);                 // (NB+1)*4 + slack
    int*            cnt     = (int*)(ws + 1600256);
    int*            cursor  = (int*)(ws + 3200256);
    int2*           edat    = (int2*)(ws + 4800256);          // 12.8 MB
    unsigned short* nfb     = (unsigned short*)(ws + 17600256);
    unsigned short* hbfA    = (unsigned short*)(ws + 30400256);
    unsigned short* hbfB    = (unsigned short*)(ws + 43200256);
    unsigned short* gbfA    = (unsigned short*)(ws + 56000256);
    unsigned short* gbfB    = (unsigned short*)(ws + 68800256);
    unsigned short* WL      = (unsigned short*)(ws + 81600256);   // 3*64*320
    unsigned short* WP      = (unsigned short*)(ws + 81600256 + 122880);
    unsigned short* WT2     = (unsigned short*)(ws + 81600256 + 122880 + 49152);
    int*            blksum  = (int*)(ws + 81600256 + 122880 + 49152 + 49152);
    int*            blkoff  = blksum + 512;

    // CSR build (layer-invariant)
    hipMemsetAsync(cnt, 0, NB * sizeof(int), stream);
    k_hist<<<2048, 256, 0, stream>>>(dst, rel, cnt);
    k_scan_local<<<NBLK_SCAN, 1024, 0, stream>>>(cnt, row_ptr, blksum);
    k_scan_blk<<<1, 512, 0, stream>>>(blksum, blkoff, row_ptr);
    k_scan_add<<<NBLK_SCAN, 1024, 0, stream>>>(row_ptr, blkoff, cursor);
    k_reorder<<<2048, 256, 0, stream>>>(src, dst, rel, ew, cursor, edat);

    // bf16 conversions
    k_cvt_x<<<25000, 256, 0, stream>>>(node_feat, nfb);
    k_cvt_w<<<432, 256, 0, stream>>>(lin_w, self_w, pw, tw, WL, WP, WT2);

    const unsigned short* cur  = nfb;
    const unsigned short* prev = nfb;
    unsigned short* hbuf[3] = { hbfA, hbfB, hbfA };
    unsigned short* gbuf[3] = { gbfA, gbfB, gbfA };

    for (int i = 0; i < 3; ++i) {
        int lastL = (i == 2);
        k_layer<<<NN / 16, 256, 0, stream>>>(
            cur, prev, row_ptr, edat,
            WL  + (size_t)i * 64 * 320,
            WP  + (size_t)i * 64 * 128,
            WT2 + (size_t)i * 64 * 128,
            lin_b + (size_t)i * 64, self_b + (size_t)i * 64,
            pb + (size_t)i * 64, tb + (size_t)i * 64,
            hbuf[i], gbuf[i], outf, lastL);
        cur  = gbuf[i];
        prev = hbuf[i];
    }
}